// Round 7
// baseline (523.735 us; speedup 1.0000x reference)
//
#include <hip/hip_runtime.h>
#include <math.h>

#define BB 2
#define NN 2048
#define DD 512
#define HH 8
#define DHH 64
#define FF 2048
#define MROWS (BB*NN)   // 4096
#define LN_EPS 1e-5f
#define PHASE_ALPHA 0.1f
#define PI_F 3.14159265358979323846f
#define SCALE 0.125f    // 1/sqrt(64)
#define QLD (3*DD)      // fused QKV row stride
#define LOG2E 1.44269504088896340736f

typedef __attribute__((ext_vector_type(8))) short  bf16x8;
typedef __attribute__((ext_vector_type(4))) float  f32x4;
typedef __attribute__((ext_vector_type(4))) unsigned short us4;

__device__ __forceinline__ unsigned short f2bf(float x) {
    unsigned int u = __float_as_uint(x);
    u += 0x7fffu + ((u >> 16) & 1u);      // RNE
    return (unsigned short)(u >> 16);
}

#if __has_builtin(__builtin_amdgcn_exp2f)
#define EXP2(x) __builtin_amdgcn_exp2f(x)
#else
#define EXP2(x) exp2f(x)
#endif

__device__ __forceinline__ unsigned pk_bf16(float a, float b) {
    unsigned r;
    asm("v_cvt_pk_bf16_f32 %0, %1, %2" : "=v"(r) : "v"(a), "v"(b));
    return r;
}

// ---------------------------------------------------------------- bf16 convert
__global__ __launch_bounds__(256) void convert_bf16_kernel(
    const float* __restrict__ X, unsigned short* __restrict__ Y, int n8)
{
    int i = blockIdx.x*256 + threadIdx.x;
    if (i >= n8) return;
    const float4 a = *(const float4*)&X[i*8];
    const float4 b = *(const float4*)&X[i*8 + 4];
    uint4 o;
    o.x = (unsigned)f2bf(a.x) | ((unsigned)f2bf(a.y) << 16);
    o.y = (unsigned)f2bf(a.z) | ((unsigned)f2bf(a.w) << 16);
    o.z = (unsigned)f2bf(b.x) | ((unsigned)f2bf(b.y) << 16);
    o.w = (unsigned)f2bf(b.z) | ((unsigned)f2bf(b.w) << 16);
    *(uint4*)&Y[i*8] = o;
}

// ------------------------------------------- weight transpose f32[K][N] -> bf16[N][K]
__global__ __launch_bounds__(256) void wtrans_kernel(
    const float* __restrict__ W, unsigned short* __restrict__ WT, int K, int N)
{
    __shared__ unsigned short T[32][33];
    const int k0 = blockIdx.y*32, n0 = blockIdx.x*32;
    const int r = threadIdx.x >> 3, cc = (threadIdx.x & 7)*4;
    float4 v = *(const float4*)&W[(size_t)(k0 + r)*N + n0 + cc];
    T[cc+0][r] = f2bf(v.x); T[cc+1][r] = f2bf(v.y);
    T[cc+2][r] = f2bf(v.z); T[cc+3][r] = f2bf(v.w);
    __syncthreads();
    us4 o; o.x = T[r][cc]; o.y = T[r][cc+1]; o.z = T[r][cc+2]; o.w = T[r][cc+3];
    *(us4*)&WT[(size_t)(n0 + r)*K + k0 + cc] = o;
}

// ------------------------------------------- V transpose (fused QKV col 1024+) -> VT[(b,h,dh)][N]
__global__ __launch_bounds__(256) void vtrans_kernel(
    const unsigned short* __restrict__ qkv, unsigned short* __restrict__ VT)
{
    __shared__ unsigned short T[32][33];
    const int b = blockIdx.z;
    const int n0 = blockIdx.x*32, c0 = blockIdx.y*32;
    const int r = threadIdx.x >> 3, cc = (threadIdx.x & 7)*4;
    us4 v = *(const us4*)&qkv[((size_t)b*NN + n0 + r)*QLD + 2*DD + c0 + cc];
    T[cc+0][r] = v.x; T[cc+1][r] = v.y; T[cc+2][r] = v.z; T[cc+3][r] = v.w;
    __syncthreads();
    const int cg = c0 + r;                 // global col = h*64+dh
    const int hh = cg >> 6, dh = cg & 63;
    us4 o; o.x = T[r][cc]; o.y = T[r][cc+1]; o.z = T[r][cc+2]; o.w = T[r][cc+3];
    *(us4*)&VT[(((size_t)b*HH + hh)*DHH + dh)*NN + n0 + cc] = o;
}

// ---------------------------------------------------------------- MFMA GEMM
// C[M,Nc] = A[M,K] @ BT[Nc,K]^T, bf16 row-major K-contiguous, BK=64.
// 256 threads = 4 waves (2x2); wave tile (BM/2)x(BN/2); frags FM=BM/32, FN=BN/32.
// SPLITK>1: blockIdx.z selects K-chunk; ATOMIC=1 does f32 atomicAdd epilogue.
template<int BM, int BN, int SPLITK, int OUTBF16, int BIAS, int ACT, int ATOMIC>
__global__ __launch_bounds__(256, 2) void mfma_gemm(
    const unsigned short* __restrict__ A, const unsigned short* __restrict__ BT,
    const float* __restrict__ bias, void* __restrict__ Cout,
    int M, int Nc, int K)
{
    constexpr int FM = BM/32, FN = BN/32;
    constexpr int ROWS = BM + BN;
    constexpr int NLOAD = ROWS*8/256;
    __shared__ unsigned short Ss[ROWS][72];   // A rows [0,BM), B rows [BM,BM+BN)

    const int tid = threadIdx.x;
    const int w = tid >> 6, lane = tid & 63;
    const int c = lane & 15, g = lane >> 4;
    const int wr = w >> 1, wc = w & 1;
    const int bm = blockIdx.y*BM, bn = blockIdx.x*BN;
    const int k0 = (SPLITK > 1) ? blockIdx.z * (K / SPLITK) : 0;
    const int NT = (K / SPLITK) / 64;

    f32x4 zero = {0.f, 0.f, 0.f, 0.f};
    f32x4 acc[FM][FN];
    #pragma unroll
    for (int i = 0; i < FM; ++i)
        #pragma unroll
        for (int j = 0; j < FN; ++j) acc[i][j] = zero;

    uint4 pf[NLOAD];
    #pragma unroll
    for (int l = 0; l < NLOAD; ++l) {
        const int i = tid + l*256;
        const int r = i >> 3, kc = (i & 7)*8;
        const unsigned short* src = (r < BM) ? &A [(size_t)(bm + r)*K + k0 + kc]
                                             : &BT[(size_t)(bn + r - BM)*K + k0 + kc];
        pf[l] = *(const uint4*)src;
    }

    for (int kt = 0; kt < NT; ++kt) {
        __syncthreads();
        #pragma unroll
        for (int l = 0; l < NLOAD; ++l) {
            const int i = tid + l*256;
            *(uint4*)&Ss[i >> 3][(i & 7)*8] = pf[l];
        }
        __syncthreads();
        if (kt + 1 < NT) {
            #pragma unroll
            for (int l = 0; l < NLOAD; ++l) {
                const int i = tid + l*256;
                const int r = i >> 3, kc = (i & 7)*8;
                const unsigned short* src = (r < BM)
                    ? &A [(size_t)(bm + r)*K + k0 + (kt+1)*64 + kc]
                    : &BT[(size_t)(bn + r - BM)*K + k0 + (kt+1)*64 + kc];
                pf[l] = *(const uint4*)src;
            }
        }
        #pragma unroll
        for (int ks = 0; ks < 2; ++ks) {
            bf16x8 af[FM], bfr[FN];
            #pragma unroll
            for (int mf = 0; mf < FM; ++mf)
                af[mf] = *(const bf16x8*)&Ss[wr*(BM/2) + mf*16 + c][ks*32 + g*8];
            #pragma unroll
            for (int nf = 0; nf < FN; ++nf)
                bfr[nf] = *(const bf16x8*)&Ss[BM + wc*(BN/2) + nf*16 + c][ks*32 + g*8];
            #pragma unroll
            for (int mf = 0; mf < FM; ++mf)
                #pragma unroll
                for (int nf = 0; nf < FN; ++nf)
                    acc[mf][nf] = __builtin_amdgcn_mfma_f32_16x16x32_bf16(
                        af[mf], bfr[nf], acc[mf][nf], 0, 0, 0);
        }
    }

    #pragma unroll
    for (int mf = 0; mf < FM; ++mf)
        #pragma unroll
        for (int nf = 0; nf < FN; ++nf) {
            const int col = bn + wc*(BN/2) + nf*16 + c;
            const float bv = BIAS ? bias[col] : 0.f;
            #pragma unroll
            for (int r = 0; r < 4; ++r) {
                const int row = bm + wr*(BM/2) + mf*16 + g*4 + r;
                float x = acc[mf][nf][r] + bv;
                if (ACT == 1) x = 0.5f * x * (1.f + erff(x * 0.70710678118654752f));
                if (ATOMIC)       atomicAdd(&((float*)Cout)[(size_t)row*Nc + col], x);
                else if (OUTBF16) ((unsigned short*)Cout)[(size_t)row*Nc + col] = f2bf(x);
                else              ((float*)Cout)[(size_t)row*Nc + col] = x;
            }
        }
}

// ------------------------------------------------- phase projection + cos/sin (-> [b,h][n])
__global__ __launch_bounds__(256) void phase_proj_kernel(
    const float* __restrict__ X, const float* __restrict__ Wp,
    const float* __restrict__ bp, float* __restrict__ cosPt, float* __restrict__ sinPt)
{
    __shared__ float Wl[DD*HH];
    for (int i = threadIdx.x; i < DD*HH; i += 256) Wl[i] = Wp[i];
    __syncthreads();
    int row = blockIdx.x*32 + (threadIdx.x >> 3);
    int hh  = threadIdx.x & 7;
    const float* xr = X + (size_t)row * DD;
    float acc = bp[hh];
    for (int k = 0; k < DD; k += 4) {
        float4 xv = *(const float4*)&xr[k];
        acc += xv.x*Wl[(k  )*HH+hh] + xv.y*Wl[(k+1)*HH+hh]
             + xv.z*Wl[(k+2)*HH+hh] + xv.w*Wl[(k+3)*HH+hh];
    }
    const int b = row >> 11, n = row & (NN-1);
    cosPt[((size_t)b*HH + hh)*NN + n] = cosf(acc);
    sinPt[((size_t)b*HH + hh)*NN + n] = sinf(acc);
}

// ------------------------------------------------- final phase update
__global__ __launch_bounds__(256) void phase_update_kernel(
    const float* __restrict__ H2, const float* __restrict__ Wph,
    const float* __restrict__ bph, const float* __restrict__ phases,
    float* __restrict__ phases_out)
{
    __shared__ float Wl[DD*HH];
    for (int i = threadIdx.x; i < DD*HH; i += 256) Wl[i] = Wph[i];
    __syncthreads();
    int row = blockIdx.x*32 + (threadIdx.x >> 3);
    int hh  = threadIdx.x & 7;
    const float* xr = H2 + (size_t)row * DD;
    float acc = bph[hh];
    for (int k = 0; k < DD; k += 4) {
        float4 xv = *(const float4*)&xr[k];
        acc += xv.x*Wl[(k  )*HH+hh] + xv.y*Wl[(k+1)*HH+hh]
             + xv.z*Wl[(k+2)*HH+hh] + xv.w*Wl[(k+3)*HH+hh];
    }
    phases_out[row*HH + hh] = phases[row*HH + hh] + PHASE_ALPHA * tanhf(acc) * PI_F;
}

// ------------------------------------------------- MFMA flash attention w/ harmonic
// 32-q blocks (grid 64x8x2 = 1024 = 4 blocks/CU). 4 waves; wave w owns 32-key
// subtiles s%4==w, independent online softmax (log2 domain, exact defer-rescale),
// merged at end. Harmonic folded as st = fma(st_raw, factor, maskbias).
__global__ __launch_bounds__(256, 4) void attn_kernel(
    const unsigned short* __restrict__ qkv, const unsigned short* __restrict__ VT,
    const float* __restrict__ cosPt, const float* __restrict__ sinPt,
    const unsigned char* __restrict__ mask, unsigned short* __restrict__ msgb)
{
    __shared__ float Os[64][36];               // O^T accum [dh][q], pad 36
    __shared__ float MwS[4][32], LwS[4][32];
    __shared__ unsigned short Pl[4][32][40];   // per-wave P [q][key_rel], 80B rows

    const int tid = threadIdx.x;
    const int w = tid >> 6, lane = tid & 63;
    const int c = lane & 15, g = lane >> 4;
    const int qBase = blockIdx.x * 32;
    const int hh = blockIdx.y, b = blockIdx.z;
    const size_t rowOff = (size_t)b * NN;
    const int bh = b*HH + hh;
    const size_t cosBase = (size_t)bh * NN;
    const float A = 0.5f * SCALE * LOG2E;      // harmonic+scale+log2e fold

    for (int i = tid; i < 64*36; i += 256) ((float*)Os)[i] = 0.f;

    // Q B-frags (held in registers for the whole block)
    bf16x8 qf[2][2];
    #pragma unroll
    for (int nf = 0; nf < 2; ++nf)
        #pragma unroll
        for (int ks = 0; ks < 2; ++ks)
            qf[nf][ks] = *(const bf16x8*)&qkv[(rowOff + qBase + nf*16 + c)*QLD
                                              + hh*DHH + ks*32 + g*8];
    float cqs[2], sqs[2];
    #pragma unroll
    for (int nf = 0; nf < 2; ++nf) {
        cqs[nf] = A * cosPt[cosBase + qBase + nf*16 + c];
        sqs[nf] = A * sinPt[cosBase + qBase + nf*16 + c];
    }

    f32x4 zero = {0.f, 0.f, 0.f, 0.f};
    f32x4 acc[4][2];
    #pragma unroll
    for (int i = 0; i < 4; ++i)
        #pragma unroll
        for (int j = 0; j < 2; ++j) acc[i][j] = zero;
    float mst[2] = {-INFINITY, -INFINITY}, lst[2] = {0.f, 0.f};

    __syncthreads();   // Os zeroed

    for (int s = w; s < NN/32; s += 4) {
        const int kb0 = s * 32;
        // ---- S^T = K·Q^T (32 keys x 32 q)
        f32x4 st[2][2];
        #pragma unroll
        for (int mf = 0; mf < 2; ++mf) {
            bf16x8 kf0 = *(const bf16x8*)&qkv[(rowOff + kb0 + mf*16 + c)*QLD + DD + hh*DHH + g*8];
            bf16x8 kf1 = *(const bf16x8*)&qkv[(rowOff + kb0 + mf*16 + c)*QLD + DD + hh*DHH + 32 + g*8];
            #pragma unroll
            for (int nf = 0; nf < 2; ++nf) {
                st[mf][nf] = __builtin_amdgcn_mfma_f32_16x16x32_bf16(kf0, qf[nf][0], zero, 0, 0, 0);
                st[mf][nf] = __builtin_amdgcn_mfma_f32_16x16x32_bf16(kf1, qf[nf][1], st[mf][nf], 0, 0, 0);
            }
        }
        // ---- harmonic factor (log2 dom) + mask bias: st = fma(st_raw, factor, mbias)
        #pragma unroll
        for (int mf = 0; mf < 2; ++mf) {
            const int keyb = kb0 + mf*16 + g*4;
            const f32x4 ck = *(const f32x4*)&cosPt[cosBase + keyb];
            const f32x4 sk = *(const f32x4*)&sinPt[cosBase + keyb];
            const unsigned int mk = *(const unsigned int*)&mask[rowOff + keyb];
            f32x4 mbias;
            #pragma unroll
            for (int r = 0; r < 4; ++r)
                mbias[r] = ((mk >> (8*r)) & 0xff) ? -INFINITY : 0.f;
            #pragma unroll
            for (int nf = 0; nf < 2; ++nf)
                #pragma unroll
                for (int r = 0; r < 4; ++r) {
                    const float factor = fmaf(cqs[nf], ck[r], fmaf(sqs[nf], sk[r], A));
                    st[mf][nf][r] = fmaf(st[mf][nf][r], factor, mbias[r]);
                }
        }
        // ---- online softmax per q-column, log2 domain, exact defer-rescale
        #pragma unroll
        for (int nf = 0; nf < 2; ++nf) {
            float tmax = fmaxf(fmaxf(st[0][nf][0], st[0][nf][1]), fmaxf(st[0][nf][2], st[0][nf][3]));
            tmax = fmaxf(tmax, fmaxf(fmaxf(st[1][nf][0], st[1][nf][1]), fmaxf(st[1][nf][2], st[1][nf][3])));
            tmax = fmaxf(tmax, __shfl_xor(tmax, 16));
            tmax = fmaxf(tmax, __shfl_xor(tmax, 32));
            if (!__all(tmax <= mst[nf])) {
                const float mnew = fmaxf(mst[nf], tmax);
                const float corr = (mst[nf] == -INFINITY) ? 0.f : EXP2(mst[nf] - mnew);
                lst[nf] *= corr;
                #pragma unroll
                for (int mo = 0; mo < 4; ++mo)
                    #pragma unroll
                    for (int r = 0; r < 4; ++r) acc[mo][nf][r] *= corr;
                mst[nf] = mnew;
            }
            const float mcur = mst[nf];
            float psum = 0.f;
            unsigned short* prow = &Pl[w][nf*16 + c][0];
            #pragma unroll
            for (int mf = 0; mf < 2; ++mf) {
                float p0 = EXP2(st[mf][nf][0] - mcur);
                float p1 = EXP2(st[mf][nf][1] - mcur);
                float p2 = EXP2(st[mf][nf][2] - mcur);
                float p3 = EXP2(st[mf][nf][3] - mcur);
                psum += (p0 + p1) + (p2 + p3);
                uint2 pk; pk.x = pk_bf16(p0, p1); pk.y = pk_bf16(p2, p3);
                *(uint2*)&prow[mf*16 + g*4] = pk;
            }
            psum += __shfl_xor(psum, 16);
            psum += __shfl_xor(psum, 32);
            lst[nf] += psum;
        }
        // ---- O^T += V^T · P^T  (wave-private, no barrier needed)
        bf16x8 vf[4], pfr[2];
        #pragma unroll
        for (int mo = 0; mo < 4; ++mo)
            vf[mo] = *(const bf16x8*)&VT[((size_t)bh*DHH + mo*16 + c)*NN + kb0 + g*8];
        #pragma unroll
        for (int nf = 0; nf < 2; ++nf)
            pfr[nf] = *(const bf16x8*)&Pl[w][nf*16 + c][g*8];
        #pragma unroll
        for (int mo = 0; mo < 4; ++mo)
            #pragma unroll
            for (int nf = 0; nf < 2; ++nf)
                acc[mo][nf] = __builtin_amdgcn_mfma_f32_16x16x32_bf16(
                    vf[mo], pfr[nf], acc[mo][nf], 0, 0, 0);
    }

    // ---- merge the 4 wave-partials
    if (lane < 16) {
        #pragma unroll
        for (int nf = 0; nf < 2; ++nf) {
            MwS[w][nf*16 + lane] = mst[nf];
            LwS[w][nf*16 + lane] = lst[nf];
        }
    }
    __syncthreads();
    float fac[2];
    #pragma unroll
    for (int nf = 0; nf < 2; ++nf) {
        const int q = nf*16 + c;
        float M = fmaxf(fmaxf(MwS[0][q], MwS[1][q]), fmaxf(MwS[2][q], MwS[3][q]));
        float L = LwS[0][q]*EXP2(MwS[0][q]-M) + LwS[1][q]*EXP2(MwS[1][q]-M)
                + LwS[2][q]*EXP2(MwS[2][q]-M) + LwS[3][q]*EXP2(MwS[3][q]-M);
        fac[nf] = EXP2(mst[nf] - M) / L;
    }
    #pragma unroll
    for (int mo = 0; mo < 4; ++mo)
        #pragma unroll
        for (int nf = 0; nf < 2; ++nf)
            #pragma unroll
            for (int r = 0; r < 4; ++r)
                atomicAdd(&Os[mo*16 + g*4 + r][nf*16 + c], acc[mo][nf][r] * fac[nf]);
    __syncthreads();

    // ---- transpose-write msgb[q][h*64+dh] bf16 (32 q x 64 dh)
    const int q = tid >> 3, dh0 = (tid & 7) * 8;
    unsigned int ov[4];
    #pragma unroll
    for (int i = 0; i < 4; ++i)
        ov[i] = (unsigned)f2bf(Os[dh0 + 2*i][q]) | ((unsigned)f2bf(Os[dh0 + 2*i + 1][q]) << 16);
    unsigned short* op = &msgb[(rowOff + qBase + q)*DD + hh*DHH + dh0];
    *(uint4*)&op[0] = *(uint4*)&ov[0];
}

// ------------------------------------------------- residual + LayerNorm (+delta, +bf16 copy, +ybias)
template<int WITH_DELTA, int WBF16, int YBIAS>
__global__ __launch_bounds__(256) void ln_kernel(
    const float* __restrict__ x, const float* __restrict__ y,
    const float* __restrict__ g, const float* __restrict__ bvec,
    const float* __restrict__ ybias,
    float* __restrict__ out, unsigned short* __restrict__ outb,
    const float* __restrict__ href, float* __restrict__ deltaAcc)
{
    const int row = blockIdx.x;
    const int tid = threadIdx.x;
    const size_t base = (size_t)row * DD + tid*2;
    float2 xv = *(const float2*)(x + base);
    float2 yv = *(const float2*)(y + base);
    float v0 = xv.x + yv.x;
    float v1 = xv.y + yv.y;
    if (YBIAS) { v0 += ybias[tid*2]; v1 += ybias[tid*2+1]; }
    float s  = v0 + v1;
    float sq = v0*v0 + v1*v1;
    #pragma unroll
    for (int m = 1; m < 64; m <<= 1) {
        s  += __shfl_xor(s,  m, 64);
        sq += __shfl_xor(sq, m, 64);
    }
    __shared__ float redS[4], redQ[4];
    int wv = tid >> 6;
    if ((tid & 63) == 0) { redS[wv] = s; redQ[wv] = sq; }
    __syncthreads();
    s  = redS[0] + redS[1] + redS[2] + redS[3];
    sq = redQ[0] + redQ[1] + redQ[2] + redQ[3];
    float mu  = s * (1.f/DD);
    float var = sq * (1.f/DD) - mu*mu;
    float inv = rsqrtf(var + LN_EPS);
    float o0 = (v0 - mu)*inv*g[tid*2  ] + bvec[tid*2  ];
    float o1 = (v1 - mu)*inv*g[tid*2+1] + bvec[tid*2+1];
    float2 ov; ov.x = o0; ov.y = o1;
    *(float2*)(out + base) = ov;
    if (WBF16)
        ((unsigned int*)outb)[(size_t)row*(DD/2) + tid] =
            (unsigned)f2bf(o0) | ((unsigned)f2bf(o1) << 16);

    if (WITH_DELTA) {
        float d0 = o0 - href[base], d1 = o1 - href[base + 1];
        float ds = d0*d0 + d1*d1;
        #pragma unroll
        for (int m = 1; m < 64; m <<= 1) ds += __shfl_xor(ds, m, 64);
        __shared__ float redD[4];
        if ((tid & 63) == 0) redD[wv] = ds;
        __syncthreads();
        if (tid == 0) {
            float t = redD[0] + redD[1] + redD[2] + redD[3];
            atomicAdd(deltaAcc, sqrtf(t));
        }
    }
}

__global__ void delta_finalize(const float* __restrict__ acc, float* __restrict__ out)
{
    out[0] = acc[0] * (1.f / (float)MROWS);
}

// ---------------------------------------------------------------- launch
extern "C" void kernel_launch(void* const* d_in, const int* in_sizes, int n_in,
                              void* d_out, int out_size, void* d_ws, size_t ws_size,
                              hipStream_t stream)
{
    (void)in_sizes; (void)n_in; (void)out_size; (void)ws_size;
    const float* h      = (const float*)d_in[0];
    const float* phases = (const float*)d_in[1];
    const unsigned char* mask = (const unsigned char*)d_in[2];
    const float* Wq  = (const float*)d_in[3];
    const float* Wk  = (const float*)d_in[4];
    const float* Wp  = (const float*)d_in[5];
    const float* bp  = (const float*)d_in[6];
    const float* Wv  = (const float*)d_in[7];
    const float* Wo  = (const float*)d_in[8];
    const float* W1  = (const float*)d_in[9];
    const float* b1  = (const float*)d_in[10];
    const float* W2  = (const float*)d_in[11];
    const float* b2  = (const float*)d_in[12];
    const float* g1  = (const float*)d_in[13];
    const float* be1 = (const float*)d_in[14];
    const float* g2  = (const float*)d_in[15];
    const float* be2 = (const float*)d_in[16];
    const float* Wph = (const float*)d_in[17];
    const float* bph = (const float*)d_in[18];

    char* ws = (char*)d_ws;
    const size_t MB = 1024*1024;
    unsigned short* hb   = (unsigned short*)(ws);              // 4 MB
    unsigned short* WqT  = (unsigned short*)(ws + 4*MB);       // .5  (Wq/Wk/Wv contiguous = fused BT)
    unsigned short* WkT  = (unsigned short*)(ws + 4*MB + 512*1024);
    unsigned short* WvT  = (unsigned short*)(ws + 5*MB);
    unsigned short* WoT  = (unsigned short*)(ws + 5*MB + 512*1024);
    unsigned short* W1T  = (unsigned short*)(ws + 6*MB);       // 2 MB
    unsigned short* W2T  = (unsigned short*)(ws + 8*MB);       // 2 MB
    unsigned short* qkvb = (unsigned short*)(ws + 10*MB);      // 12 MB [4096][1536]
    unsigned short* VT   = (unsigned short*)(ws + 22*MB);      // 4 MB
    unsigned short* T1b  = qkvb;                               // 16 MB alias (qkv/VT dead after attn)
    unsigned short* msgb = (unsigned short*)(ws + 26*MB);      // 4 MB
    float* mo    = (float*)(ws + 30*MB);                       // 8 MB (ffn aliases: mo dead after ln1)
    float* ffn   = mo;
    float* h1    = (float*)(ws + 38*MB);                       // 8 MB
    unsigned short* h1b = (unsigned short*)(ws + 46*MB);       // 4 MB
    float* cosPt = (float*)(ws + 50*MB);                       // 64 KB
    float* sinPt = (float*)(ws + 50*MB + 64*1024);             // 64 KB
    float* dAcc  = (float*)(ws + 50*MB + 128*1024);

    float* out_h2    = (float*)d_out;
    float* out_ph    = out_h2 + (size_t)MROWS*DD;
    float* out_delta = out_ph + MROWS*HH;

    hipMemsetAsync(dAcc, 0, sizeof(float), stream);

    dim3 blk(256);
    // bf16 conversion of h
    convert_bf16_kernel<<<dim3(MROWS*DD/8/256), blk, 0, stream>>>(h, hb, MROWS*DD/8);
    // weight transposes (f32[K][N] -> bf16[N][K])
    wtrans_kernel<<<dim3(DD/32, DD/32), blk, 0, stream>>>(Wq, WqT, DD, DD);
    wtrans_kernel<<<dim3(DD/32, DD/32), blk, 0, stream>>>(Wk, WkT, DD, DD);
    wtrans_kernel<<<dim3(DD/32, DD/32), blk, 0, stream>>>(Wv, WvT, DD, DD);
    wtrans_kernel<<<dim3(DD/32, DD/32), blk, 0, stream>>>(Wo, WoT, DD, DD);
    wtrans_kernel<<<dim3(FF/32, DD/32), blk, 0, stream>>>(W1, W1T, DD, FF);
    wtrans_kernel<<<dim3(DD/32, FF/32), blk, 0, stream>>>(W2, W2T, FF, DD);
    // phases
    phase_proj_kernel<<<dim3(MROWS/32), blk, 0, stream>>>(h, Wp, bp, cosPt, sinPt);
    // fused QKV projection: Nc = 1536, tile 64x128 -> 768 blocks
    mfma_gemm<64,128,1,1,0,0,0><<<dim3((3*DD)/128, MROWS/64), blk, 0, stream>>>(
        hb, WqT, nullptr, qkvb, MROWS, 3*DD, DD);
    vtrans_kernel<<<dim3(NN/32, DD/32, BB), blk, 0, stream>>>(qkvb, VT);
    // attention: 32-q blocks -> 1024 blocks (4/CU)
    attn_kernel<<<dim3(NN/32, HH, BB), blk, 0, stream>>>(qkvb, VT, cosPt, sinPt, mask, msgb);
    // output projection (64x64 tile -> 512 blocks) + LN1
    mfma_gemm<64,64,1,0,0,0,0><<<dim3(DD/64, MROWS/64), blk, 0, stream>>>(
        msgb, WoT, nullptr, mo, MROWS, DD, DD);
    ln_kernel<0,1,0><<<dim3(MROWS), blk, 0, stream>>>(h, mo, g1, be1, nullptr, h1, h1b, nullptr, nullptr);
    // FFN: W1 128x128 (512 blocks); W2 64x64 split-K=2 (1024 blocks, atomic f32)
    mfma_gemm<128,128,1,1,1,1,0><<<dim3(FF/128, MROWS/128), blk, 0, stream>>>(
        h1b, W1T, b1, T1b, MROWS, FF, DD);
    hipMemsetAsync(ffn, 0, (size_t)MROWS*DD*sizeof(float), stream);
    mfma_gemm<64,64,2,0,0,0,1><<<dim3(DD/64, MROWS/64, 2), blk, 0, stream>>>(
        T1b, W2T, nullptr, ffn, MROWS, DD, FF);
    ln_kernel<1,0,1><<<dim3(MROWS), blk, 0, stream>>>(h1, ffn, g2, be2, b2, out_h2, nullptr, h, dAcc);
    // phase update + delta
    phase_update_kernel<<<dim3(MROWS/32), blk, 0, stream>>>(out_h2, Wph, bph, phases, out_ph);
    delta_finalize<<<dim3(1), dim3(1), 0, stream>>>(dAcc, out_delta);
}

// Round 11
// 493.377 us; speedup vs baseline: 1.0615x; 1.0615x over previous
//
#include <hip/hip_runtime.h>
#include <math.h>

#define BB 2
#define NN 2048
#define DD 512
#define HH 8
#define DHH 64
#define FF 2048
#define MROWS (BB*NN)   // 4096
#define LN_EPS 1e-5f
#define PHASE_ALPHA 0.1f
#define PI_F 3.14159265358979323846f
#define SCALE 0.125f    // 1/sqrt(64)
#define QLD (3*DD)      // fused QKV row stride
#define LOG2E 1.44269504088896340736f

typedef __attribute__((ext_vector_type(8))) short  bf16x8;
typedef __attribute__((ext_vector_type(4))) float  f32x4;
typedef __attribute__((ext_vector_type(4))) unsigned short us4;

__device__ __forceinline__ unsigned short f2bf(float x) {
    unsigned int u = __float_as_uint(x);
    u += 0x7fffu + ((u >> 16) & 1u);      // RNE
    return (unsigned short)(u >> 16);
}

#if __has_builtin(__builtin_amdgcn_exp2f)
#define EXP2(x) __builtin_amdgcn_exp2f(x)
#else
#define EXP2(x) exp2f(x)
#endif

__device__ __forceinline__ unsigned pk_bf16(float a, float b) {
    unsigned r;
    asm("v_cvt_pk_bf16_f32 %0, %1, %2" : "=v"(r) : "v"(a), "v"(b));
    return r;
}

// ---------------------------------------------------------------- bf16 convert
__global__ __launch_bounds__(256) void convert_bf16_kernel(
    const float* __restrict__ X, unsigned short* __restrict__ Y, int n8)
{
    int i = blockIdx.x*256 + threadIdx.x;
    if (i >= n8) return;
    const float4 a = *(const float4*)&X[i*8];
    const float4 b = *(const float4*)&X[i*8 + 4];
    uint4 o;
    o.x = (unsigned)f2bf(a.x) | ((unsigned)f2bf(a.y) << 16);
    o.y = (unsigned)f2bf(a.z) | ((unsigned)f2bf(a.w) << 16);
    o.z = (unsigned)f2bf(b.x) | ((unsigned)f2bf(b.y) << 16);
    o.w = (unsigned)f2bf(b.z) | ((unsigned)f2bf(b.w) << 16);
    *(uint4*)&Y[i*8] = o;
}

// ------------------------------------------- weight transpose f32[K][N] -> bf16[N][K]
__global__ __launch_bounds__(256) void wtrans_kernel(
    const float* __restrict__ W, unsigned short* __restrict__ WT, int K, int N)
{
    __shared__ unsigned short T[32][33];
    const int k0 = blockIdx.y*32, n0 = blockIdx.x*32;
    const int r = threadIdx.x >> 3, cc = (threadIdx.x & 7)*4;
    float4 v = *(const float4*)&W[(size_t)(k0 + r)*N + n0 + cc];
    T[cc+0][r] = f2bf(v.x); T[cc+1][r] = f2bf(v.y);
    T[cc+2][r] = f2bf(v.z); T[cc+3][r] = f2bf(v.w);
    __syncthreads();
    us4 o; o.x = T[r][cc]; o.y = T[r][cc+1]; o.z = T[r][cc+2]; o.w = T[r][cc+3];
    *(us4*)&WT[(size_t)(n0 + r)*K + k0 + cc] = o;
}

// ------------------------------------------- V transpose (fused QKV col 1024+) -> VT[(b,h,dh)][N]
__global__ __launch_bounds__(256) void vtrans_kernel(
    const unsigned short* __restrict__ qkv, unsigned short* __restrict__ VT)
{
    __shared__ unsigned short T[32][33];
    const int b = blockIdx.z;
    const int n0 = blockIdx.x*32, c0 = blockIdx.y*32;
    const int r = threadIdx.x >> 3, cc = (threadIdx.x & 7)*4;
    us4 v = *(const us4*)&qkv[((size_t)b*NN + n0 + r)*QLD + 2*DD + c0 + cc];
    T[cc+0][r] = v.x; T[cc+1][r] = v.y; T[cc+2][r] = v.z; T[cc+3][r] = v.w;
    __syncthreads();
    const int cg = c0 + r;                 // global col = h*64+dh
    const int hh = cg >> 6, dh = cg & 63;
    us4 o; o.x = T[r][cc]; o.y = T[r][cc+1]; o.z = T[r][cc+2]; o.w = T[r][cc+3];
    *(us4*)&VT[(((size_t)b*HH + hh)*DHH + dh)*NN + n0 + cc] = o;
}

// ---------------------------------------------------------------- MFMA GEMM
// C[M,Nc] = A[M,K] @ BT[Nc,K]^T, bf16 row-major K-contiguous, BK=64.
// 256 threads = 4 waves (2x2); wave tile (BM/2)x(BN/2); frags FM=BM/32, FN=BN/32.
// SPLITK>1: blockIdx.z selects K-chunk; ATOMIC=1 does f32 atomicAdd epilogue.
template<int BM, int BN, int SPLITK, int OUTBF16, int BIAS, int ACT, int ATOMIC>
__global__ __launch_bounds__(256, 2) void mfma_gemm(
    const unsigned short* __restrict__ A, const unsigned short* __restrict__ BT,
    const float* __restrict__ bias, void* __restrict__ Cout,
    int M, int Nc, int K)
{
    constexpr int FM = BM/32, FN = BN/32;
    constexpr int ROWS = BM + BN;
    constexpr int NLOAD = ROWS*8/256;
    __shared__ unsigned short Ss[ROWS][72];   // A rows [0,BM), B rows [BM,BM+BN)

    const int tid = threadIdx.x;
    const int w = tid >> 6, lane = tid & 63;
    const int c = lane & 15, g = lane >> 4;
    const int wr = w >> 1, wc = w & 1;
    const int bm = blockIdx.y*BM, bn = blockIdx.x*BN;
    const int k0 = (SPLITK > 1) ? blockIdx.z * (K / SPLITK) : 0;
    const int NT = (K / SPLITK) / 64;

    f32x4 zero = {0.f, 0.f, 0.f, 0.f};
    f32x4 acc[FM][FN];
    #pragma unroll
    for (int i = 0; i < FM; ++i)
        #pragma unroll
        for (int j = 0; j < FN; ++j) acc[i][j] = zero;

    uint4 pf[NLOAD];
    #pragma unroll
    for (int l = 0; l < NLOAD; ++l) {
        const int i = tid + l*256;
        const int r = i >> 3, kc = (i & 7)*8;
        const unsigned short* src = (r < BM) ? &A [(size_t)(bm + r)*K + k0 + kc]
                                             : &BT[(size_t)(bn + r - BM)*K + k0 + kc];
        pf[l] = *(const uint4*)src;
    }

    for (int kt = 0; kt < NT; ++kt) {
        __syncthreads();
        #pragma unroll
        for (int l = 0; l < NLOAD; ++l) {
            const int i = tid + l*256;
            *(uint4*)&Ss[i >> 3][(i & 7)*8] = pf[l];
        }
        __syncthreads();
        if (kt + 1 < NT) {
            #pragma unroll
            for (int l = 0; l < NLOAD; ++l) {
                const int i = tid + l*256;
                const int r = i >> 3, kc = (i & 7)*8;
                const unsigned short* src = (r < BM)
                    ? &A [(size_t)(bm + r)*K + k0 + (kt+1)*64 + kc]
                    : &BT[(size_t)(bn + r - BM)*K + k0 + (kt+1)*64 + kc];
                pf[l] = *(const uint4*)src;
            }
        }
        #pragma unroll
        for (int ks = 0; ks < 2; ++ks) {
            bf16x8 af[FM], bfr[FN];
            #pragma unroll
            for (int mf = 0; mf < FM; ++mf)
                af[mf] = *(const bf16x8*)&Ss[wr*(BM/2) + mf*16 + c][ks*32 + g*8];
            #pragma unroll
            for (int nf = 0; nf < FN; ++nf)
                bfr[nf] = *(const bf16x8*)&Ss[BM + wc*(BN/2) + nf*16 + c][ks*32 + g*8];
            #pragma unroll
            for (int mf = 0; mf < FM; ++mf)
                #pragma unroll
                for (int nf = 0; nf < FN; ++nf)
                    acc[mf][nf] = __builtin_amdgcn_mfma_f32_16x16x32_bf16(
                        af[mf], bfr[nf], acc[mf][nf], 0, 0, 0);
        }
    }

    #pragma unroll
    for (int mf = 0; mf < FM; ++mf)
        #pragma unroll
        for (int nf = 0; nf < FN; ++nf) {
            const int col = bn + wc*(BN/2) + nf*16 + c;
            const float bv = BIAS ? bias[col] : 0.f;
            #pragma unroll
            for (int r = 0; r < 4; ++r) {
                const int row = bm + wr*(BM/2) + mf*16 + g*4 + r;
                float x = acc[mf][nf][r] + bv;
                if (ACT == 1) x = 0.5f * x * (1.f + erff(x * 0.70710678118654752f));
                if (ATOMIC)       atomicAdd(&((float*)Cout)[(size_t)row*Nc + col], x);
                else if (OUTBF16) ((unsigned short*)Cout)[(size_t)row*Nc + col] = f2bf(x);
                else              ((float*)Cout)[(size_t)row*Nc + col] = x;
            }
        }
}

// ------------------------------------------------- phase projection + cos/sin (-> [b,h][n])
__global__ __launch_bounds__(256) void phase_proj_kernel(
    const float* __restrict__ X, const float* __restrict__ Wp,
    const float* __restrict__ bp, float* __restrict__ cosPt, float* __restrict__ sinPt)
{
    __shared__ float Wl[DD*HH];
    for (int i = threadIdx.x; i < DD*HH; i += 256) Wl[i] = Wp[i];
    __syncthreads();
    int row = blockIdx.x*32 + (threadIdx.x >> 3);
    int hh  = threadIdx.x & 7;
    const float* xr = X + (size_t)row * DD;
    float acc = bp[hh];
    for (int k = 0; k < DD; k += 4) {
        float4 xv = *(const float4*)&xr[k];
        acc += xv.x*Wl[(k  )*HH+hh] + xv.y*Wl[(k+1)*HH+hh]
             + xv.z*Wl[(k+2)*HH+hh] + xv.w*Wl[(k+3)*HH+hh];
    }
    const int b = row >> 11, n = row & (NN-1);
    cosPt[((size_t)b*HH + hh)*NN + n] = cosf(acc);
    sinPt[((size_t)b*HH + hh)*NN + n] = sinf(acc);
}

// ------------------------------------------------- final phase update
__global__ __launch_bounds__(256) void phase_update_kernel(
    const float* __restrict__ H2, const float* __restrict__ Wph,
    const float* __restrict__ bph, const float* __restrict__ phases,
    float* __restrict__ phases_out)
{
    __shared__ float Wl[DD*HH];
    for (int i = threadIdx.x; i < DD*HH; i += 256) Wl[i] = Wph[i];
    __syncthreads();
    int row = blockIdx.x*32 + (threadIdx.x >> 3);
    int hh  = threadIdx.x & 7;
    const float* xr = H2 + (size_t)row * DD;
    float acc = bph[hh];
    for (int k = 0; k < DD; k += 4) {
        float4 xv = *(const float4*)&xr[k];
        acc += xv.x*Wl[(k  )*HH+hh] + xv.y*Wl[(k+1)*HH+hh]
             + xv.z*Wl[(k+2)*HH+hh] + xv.w*Wl[(k+3)*HH+hh];
    }
    phases_out[row*HH + hh] = phases[row*HH + hh] + PHASE_ALPHA * tanhf(acc) * PI_F;
}

// ------------------------------------------------- MFMA flash attention w/ harmonic
// Round-6 geometry (QB=64, 4 waves, 512 blocks, VGPR headroom) + round-7 softmax
// (log2 domain, mask-bias, cvt_pk, exact defer-rescale) + latency hiding:
// V frags issued before softmax; next-iter K frags prefetched into 2nd reg set;
// s_setprio(1) around MFMA clusters.
__global__ __launch_bounds__(256, 2) void attn_kernel(
    const unsigned short* __restrict__ qkv, const unsigned short* __restrict__ VT,
    const float* __restrict__ cosPt, const float* __restrict__ sinPt,
    const unsigned char* __restrict__ mask, unsigned short* __restrict__ msgb)
{
    __shared__ float Os[64][68];               // O^T accum [dh][q]
    __shared__ float MwS[4][64], LwS[4][64];
    __shared__ unsigned short Pl[4][64][40];   // per-wave P [q][key_rel], 80B rows

    const int tid = threadIdx.x;
    const int w = tid >> 6, lane = tid & 63;
    const int c = lane & 15, g = lane >> 4;
    const int qBase = blockIdx.x * 64;
    const int hh = blockIdx.y, b = blockIdx.z;
    const size_t rowOff = (size_t)b * NN;
    const int bh = b*HH + hh;
    const size_t cosBase = (size_t)bh * NN;
    const float A = 0.5f * SCALE * LOG2E;      // harmonic+scale+log2e fold

    for (int i = tid; i < 64*68; i += 256) ((float*)Os)[i] = 0.f;

    // Q B-frags (held in registers for the whole block)
    bf16x8 qf[4][2];
    #pragma unroll
    for (int nf = 0; nf < 4; ++nf)
        #pragma unroll
        for (int ks = 0; ks < 2; ++ks)
            qf[nf][ks] = *(const bf16x8*)&qkv[(rowOff + qBase + nf*16 + c)*QLD
                                              + hh*DHH + ks*32 + g*8];
    float cqs[4], sqs[4];
    #pragma unroll
    for (int nf = 0; nf < 4; ++nf) {
        cqs[nf] = A * cosPt[cosBase + qBase + nf*16 + c];
        sqs[nf] = A * sinPt[cosBase + qBase + nf*16 + c];
    }

    f32x4 zero = {0.f, 0.f, 0.f, 0.f};
    f32x4 acc[4][4];
    #pragma unroll
    for (int i = 0; i < 4; ++i)
        #pragma unroll
        for (int j = 0; j < 4; ++j) acc[i][j] = zero;
    float mst[4] = {-INFINITY, -INFINITY, -INFINITY, -INFINITY};
    float lst[4] = {0.f, 0.f, 0.f, 0.f};

    // K frag prologue (current set)
    const unsigned short* kbase = &qkv[rowOff*QLD + DD + hh*DHH];
    bf16x8 kcur[2][2], knxt[2][2];
    {
        const int kb0 = w * 32;
        #pragma unroll
        for (int mf = 0; mf < 2; ++mf)
            #pragma unroll
            for (int ks = 0; ks < 2; ++ks)
                kcur[mf][ks] = *(const bf16x8*)&kbase[(size_t)(kb0 + mf*16 + c)*QLD + ks*32 + g*8];
    }

    __syncthreads();   // Os zeroed

    for (int s = w; s < NN/32; s += 4) {
        const int kb0 = s * 32;
        // ---- V frags for THIS subtile: issue now, consumed after softmax
        bf16x8 vf[4];
        #pragma unroll
        for (int mo = 0; mo < 4; ++mo)
            vf[mo] = *(const bf16x8*)&VT[((size_t)bh*DHH + mo*16 + c)*NN + kb0 + g*8];

        // ---- S^T = K·Q^T (32 keys x 64 q)
        f32x4 st[2][4];
        __builtin_amdgcn_s_setprio(1);
        #pragma unroll
        for (int mf = 0; mf < 2; ++mf)
            #pragma unroll
            for (int nf = 0; nf < 4; ++nf) {
                st[mf][nf] = __builtin_amdgcn_mfma_f32_16x16x32_bf16(kcur[mf][0], qf[nf][0], zero, 0, 0, 0);
                st[mf][nf] = __builtin_amdgcn_mfma_f32_16x16x32_bf16(kcur[mf][1], qf[nf][1], st[mf][nf], 0, 0, 0);
            }
        __builtin_amdgcn_s_setprio(0);

        // ---- prefetch next subtile's K frags (latency hides under softmax+PV)
        {
            const int sn = (s + 4 < NN/32) ? s + 4 : s;
            const int kn0 = sn * 32;
            #pragma unroll
            for (int mf = 0; mf < 2; ++mf)
                #pragma unroll
                for (int ks = 0; ks < 2; ++ks)
                    knxt[mf][ks] = *(const bf16x8*)&kbase[(size_t)(kn0 + mf*16 + c)*QLD + ks*32 + g*8];
        }

        // ---- harmonic factor (log2 dom) + mask bias: st = fma(st_raw, factor, mbias)
        #pragma unroll
        for (int mf = 0; mf < 2; ++mf) {
            const int keyb = kb0 + mf*16 + g*4;
            const f32x4 ck = *(const f32x4*)&cosPt[cosBase + keyb];
            const f32x4 sk = *(const f32x4*)&sinPt[cosBase + keyb];
            const unsigned int mk = *(const unsigned int*)&mask[rowOff + keyb];
            f32x4 mbias;
            #pragma unroll
            for (int r = 0; r < 4; ++r)
                mbias[r] = ((mk >> (8*r)) & 0xff) ? -INFINITY : 0.f;
            #pragma unroll
            for (int nf = 0; nf < 4; ++nf)
                #pragma unroll
                for (int r = 0; r < 4; ++r) {
                    const float factor = fmaf(cqs[nf], ck[r], fmaf(sqs[nf], sk[r], A));
                    st[mf][nf][r] = fmaf(st[mf][nf][r], factor, mbias[r]);
                }
        }

        // ---- online softmax per q-column, log2 domain, exact defer-rescale
        #pragma unroll
        for (int nf = 0; nf < 4; ++nf) {
            float tmax = fmaxf(fmaxf(st[0][nf][0], st[0][nf][1]), fmaxf(st[0][nf][2], st[0][nf][3]));
            tmax = fmaxf(tmax, fmaxf(fmaxf(st[1][nf][0], st[1][nf][1]), fmaxf(st[1][nf][2], st[1][nf][3])));
            tmax = fmaxf(tmax, __shfl_xor(tmax, 16));
            tmax = fmaxf(tmax, __shfl_xor(tmax, 32));
            if (!__all(tmax <= mst[nf])) {
                const float mnew = fmaxf(mst[nf], tmax);
                const float corr = (mst[nf] == -INFINITY) ? 0.f : EXP2(mst[nf] - mnew);
                lst[nf] *= corr;
                #pragma unroll
                for (int mo = 0; mo < 4; ++mo)
                    #pragma unroll
                    for (int r = 0; r < 4; ++r) acc[mo][nf][r] *= corr;
                mst[nf] = mnew;
            }
            const float mcur = mst[nf];
            float psum = 0.f;
            unsigned short* prow = &Pl[w][nf*16 + c][0];
            #pragma unroll
            for (int mf = 0; mf < 2; ++mf) {
                float p0 = EXP2(st[mf][nf][0] - mcur);
                float p1 = EXP2(st[mf][nf][1] - mcur);
                float p2 = EXP2(st[mf][nf][2] - mcur);
                float p3 = EXP2(st[mf][nf][3] - mcur);
                psum += (p0 + p1) + (p2 + p3);
                uint2 pk; pk.x = pk_bf16(p0, p1); pk.y = pk_bf16(p2, p3);
                *(uint2*)&prow[mf*16 + g*4] = pk;
            }
            psum += __shfl_xor(psum, 16);
            psum += __shfl_xor(psum, 32);
            lst[nf] += psum;
        }

        // ---- O^T += V^T · P^T  (wave-private, no barrier needed)
        bf16x8 pfr[4];
        #pragma unroll
        for (int nf = 0; nf < 4; ++nf)
            pfr[nf] = *(const bf16x8*)&Pl[w][nf*16 + c][g*8];
        __builtin_amdgcn_s_setprio(1);
        #pragma unroll
        for (int mo = 0; mo < 4; ++mo)
            #pragma unroll
            for (int nf = 0; nf < 4; ++nf)
                acc[mo][nf] = __builtin_amdgcn_mfma_f32_16x16x32_bf16(
                    vf[mo], pfr[nf], acc[mo][nf], 0, 0, 0);
        __builtin_amdgcn_s_setprio(0);

        // rotate K reg sets
        #pragma unroll
        for (int mf = 0; mf < 2; ++mf)
            #pragma unroll
            for (int ks = 0; ks < 2; ++ks)
                kcur[mf][ks] = knxt[mf][ks];
    }

    // ---- merge the 4 wave-partials
    if (lane < 16) {
        #pragma unroll
        for (int nf = 0; nf < 4; ++nf) {
            MwS[w][nf*16 + lane] = mst[nf];
            LwS[w][nf*16 + lane] = lst[nf];
        }
    }
    __syncthreads();
    float fac[4];
    #pragma unroll
    for (int nf = 0; nf < 4; ++nf) {
        const int q = nf*16 + c;
        float M = fmaxf(fmaxf(MwS[0][q], MwS[1][q]), fmaxf(MwS[2][q], MwS[3][q]));
        float L = LwS[0][q]*EXP2(MwS[0][q]-M) + LwS[1][q]*EXP2(MwS[1][q]-M)
                + LwS[2][q]*EXP2(MwS[2][q]-M) + LwS[3][q]*EXP2(MwS[3][q]-M);
        fac[nf] = EXP2(mst[nf] - M) / L;
    }
    #pragma unroll
    for (int mo = 0; mo < 4; ++mo)
        #pragma unroll
        for (int nf = 0; nf < 4; ++nf)
            #pragma unroll
            for (int r = 0; r < 4; ++r)
                atomicAdd(&Os[mo*16 + g*4 + r][nf*16 + c], acc[mo][nf][r] * fac[nf]);
    __syncthreads();

    // ---- transpose-write msgb[q][h*64+dh] bf16
    const int q = tid >> 2, dh0 = (tid & 3) * 16;
    unsigned int ov[8];
    #pragma unroll
    for (int i = 0; i < 8; ++i)
        ov[i] = (unsigned)f2bf(Os[dh0 + 2*i][q]) | ((unsigned)f2bf(Os[dh0 + 2*i + 1][q]) << 16);
    unsigned short* op = &msgb[(rowOff + qBase + q)*DD + hh*DHH + dh0];
    *(uint4*)&op[0] = *(uint4*)&ov[0];
    *(uint4*)&op[8] = *(uint4*)&ov[4];
}

// ------------------------------------------------- residual + LayerNorm (+delta, +bf16 copy, +ybias)
template<int WITH_DELTA, int WBF16, int YBIAS>
__global__ __launch_bounds__(256) void ln_kernel(
    const float* __restrict__ x, const float* __restrict__ y,
    const float* __restrict__ g, const float* __restrict__ bvec,
    const float* __restrict__ ybias,
    float* __restrict__ out, unsigned short* __restrict__ outb,
    const float* __restrict__ href, float* __restrict__ deltaAcc)
{
    const int row = blockIdx.x;
    const int tid = threadIdx.x;
    const size_t base = (size_t)row * DD + tid*2;
    float2 xv = *(const float2*)(x + base);
    float2 yv = *(const float2*)(y + base);
    float v0 = xv.x + yv.x;
    float v1 = xv.y + yv.y;
    if (YBIAS) { v0 += ybias[tid*2]; v1 += ybias[tid*2+1]; }
    float s  = v0 + v1;
    float sq = v0*v0 + v1*v1;
    #pragma unroll
    for (int m = 1; m < 64; m <<= 1) {
        s  += __shfl_xor(s,  m, 64);
        sq += __shfl_xor(sq, m, 64);
    }
    __shared__ float redS[4], redQ[4];
    int wv = tid >> 6;
    if ((tid & 63) == 0) { redS[wv] = s; redQ[wv] = sq; }
    __syncthreads();
    s  = redS[0] + redS[1] + redS[2] + redS[3];
    sq = redQ[0] + redQ[1] + redQ[2] + redQ[3];
    float mu  = s * (1.f/DD);
    float var = sq * (1.f/DD) - mu*mu;
    float inv = rsqrtf(var + LN_EPS);
    float o0 = (v0 - mu)*inv*g[tid*2  ] + bvec[tid*2  ];
    float o1 = (v1 - mu)*inv*g[tid*2+1] + bvec[tid*2+1];
    float2 ov; ov.x = o0; ov.y = o1;
    *(float2*)(out + base) = ov;
    if (WBF16)
        ((unsigned int*)outb)[(size_t)row*(DD/2) + tid] =
            (unsigned)f2bf(o0) | ((unsigned)f2bf(o1) << 16);

    if (WITH_DELTA) {
        float d0 = o0 - href[base], d1 = o1 - href[base + 1];
        float ds = d0*d0 + d1*d1;
        #pragma unroll
        for (int m = 1; m < 64; m <<= 1) ds += __shfl_xor(ds, m, 64);
        __shared__ float redD[4];
        if ((tid & 63) == 0) redD[wv] = ds;
        __syncthreads();
        if (tid == 0) {
            float t = redD[0] + redD[1] + redD[2] + redD[3];
            atomicAdd(deltaAcc, sqrtf(t));
        }
    }
}

__global__ void delta_finalize(const float* __restrict__ acc, float* __restrict__ out)
{
    out[0] = acc[0] * (1.f / (float)MROWS);
}

// ---------------------------------------------------------------- launch
extern "C" void kernel_launch(void* const* d_in, const int* in_sizes, int n_in,
                              void* d_out, int out_size, void* d_ws, size_t ws_size,
                              hipStream_t stream)
{
    (void)in_sizes; (void)n_in; (void)out_size; (void)ws_size;
    const float* h      = (const float*)d_in[0];
    const float* phases = (const float*)d_in[1];
    const unsigned char* mask = (const unsigned char*)d_in[2];
    const float* Wq  = (const float*)d_in[3];
    const float* Wk  = (const float*)d_in[4];
    const float* Wp  = (const float*)d_in[5];
    const float* bp  = (const float*)d_in[6];
    const float* Wv  = (const float*)d_in[7];
    const float* Wo  = (const float*)d_in[8];
    const float* W1  = (const float*)d_in[9];
    const float* b1  = (const float*)d_in[10];
    const float* W2  = (const float*)d_in[11];
    const float* b2  = (const float*)d_in[12];
    const float* g1  = (const float*)d_in[13];
    const float* be1 = (const float*)d_in[14];
    const float* g2  = (const float*)d_in[15];
    const float* be2 = (const float*)d_in[16];
    const float* Wph = (const float*)d_in[17];
    const float* bph = (const float*)d_in[18];

    char* ws = (char*)d_ws;
    const size_t MB = 1024*1024;
    unsigned short* hb   = (unsigned short*)(ws);              // 4 MB
    unsigned short* WqT  = (unsigned short*)(ws + 4*MB);       // .5  (Wq/Wk/Wv contiguous = fused BT)
    unsigned short* WkT  = (unsigned short*)(ws + 4*MB + 512*1024);
    unsigned short* WvT  = (unsigned short*)(ws + 5*MB);
    unsigned short* WoT  = (unsigned short*)(ws + 5*MB + 512*1024);
    unsigned short* W1T  = (unsigned short*)(ws + 6*MB);       // 2 MB
    unsigned short* W2T  = (unsigned short*)(ws + 8*MB);       // 2 MB
    unsigned short* qkvb = (unsigned short*)(ws + 10*MB);      // 12 MB [4096][1536]
    unsigned short* VT   = (unsigned short*)(ws + 22*MB);      // 4 MB
    unsigned short* T1b  = qkvb;                               // 16 MB alias (qkv/VT dead after attn)
    unsigned short* msgb = (unsigned short*)(ws + 26*MB);      // 4 MB
    float* mo    = (float*)(ws + 30*MB);                       // 8 MB (ffn aliases: mo dead after ln1)
    float* ffn   = mo;
    float* h1    = (float*)(ws + 38*MB);                       // 8 MB
    unsigned short* h1b = (unsigned short*)(ws + 46*MB);       // 4 MB
    float* cosPt = (float*)(ws + 50*MB);                       // 64 KB
    float* sinPt = (float*)(ws + 50*MB + 64*1024);             // 64 KB
    float* dAcc  = (float*)(ws + 50*MB + 128*1024);

    float* out_h2    = (float*)d_out;
    float* out_ph    = out_h2 + (size_t)MROWS*DD;
    float* out_delta = out_ph + MROWS*HH;

    hipMemsetAsync(dAcc, 0, sizeof(float), stream);

    dim3 blk(256);
    // bf16 conversion of h
    convert_bf16_kernel<<<dim3(MROWS*DD/8/256), blk, 0, stream>>>(h, hb, MROWS*DD/8);
    // weight transposes (f32[K][N] -> bf16[N][K])
    wtrans_kernel<<<dim3(DD/32, DD/32), blk, 0, stream>>>(Wq, WqT, DD, DD);
    wtrans_kernel<<<dim3(DD/32, DD/32), blk, 0, stream>>>(Wk, WkT, DD, DD);
    wtrans_kernel<<<dim3(DD/32, DD/32), blk, 0, stream>>>(Wv, WvT, DD, DD);
    wtrans_kernel<<<dim3(DD/32, DD/32), blk, 0, stream>>>(Wo, WoT, DD, DD);
    wtrans_kernel<<<dim3(FF/32, DD/32), blk, 0, stream>>>(W1, W1T, DD, FF);
    wtrans_kernel<<<dim3(DD/32, FF/32), blk, 0, stream>>>(W2, W2T, FF, DD);
    // phases
    phase_proj_kernel<<<dim3(MROWS/32), blk, 0, stream>>>(h, Wp, bp, cosPt, sinPt);
    // fused QKV projection: Nc = 1536, tile 64x128 -> 768 blocks
    mfma_gemm<64,128,1,1,0,0,0><<<dim3((3*DD)/128, MROWS/64), blk, 0, stream>>>(
        hb, WqT, nullptr, qkvb, MROWS, 3*DD, DD);
    vtrans_kernel<<<dim3(NN/32, DD/32, BB), blk, 0, stream>>>(qkvb, VT);
    // attention: 64-q blocks -> 512 blocks (2/CU), VGPR headroom for prefetch
    attn_kernel<<<dim3(NN/64, HH, BB), blk, 0, stream>>>(qkvb, VT, cosPt, sinPt, mask, msgb);
    // output projection (64x64 tile -> 512 blocks) + LN1
    mfma_gemm<64,64,1,0,0,0,0><<<dim3(DD/64, MROWS/64), blk, 0, stream>>>(
        msgb, WoT, nullptr, mo, MROWS, DD, DD);
    ln_kernel<0,1,0><<<dim3(MROWS), blk, 0, stream>>>(h, mo, g1, be1, nullptr, h1, h1b, nullptr, nullptr);
    // FFN: W1 128x128 (512 blocks); W2 64x64 split-K=2 (1024 blocks, atomic f32)
    mfma_gemm<128,128,1,1,1,1,0><<<dim3(FF/128, MROWS/128), blk, 0, stream>>>(
        h1b, W1T, b1, T1b, MROWS, FF, DD);
    hipMemsetAsync(ffn, 0, (size_t)MROWS*DD*sizeof(float), stream);
    mfma_gemm<64,64,2,0,0,0,1><<<dim3(DD/64, MROWS/64, 2), blk, 0, stream>>>(
        T1b, W2T, nullptr, ffn, MROWS, DD, FF);
    ln_kernel<1,0,1><<<dim3(MROWS), blk, 0, stream>>>(h1, ffn, g2, be2, b2, out_h2, nullptr, h, dAcc);
    // phase update + delta
    phase_update_kernel<<<dim3(MROWS/32), blk, 0, stream>>>(out_h2, Wph, bph, phases, out_ph);
    delta_finalize<<<dim3(1), dim3(1), 0, stream>>>(dAcc, out_delta);
}